// Round 1
// baseline (692.040 us; speedup 1.0000x reference)
//
#include <hip/hip_runtime.h>

#define DD 128
#define GG 256

// ---------------- degree accumulation ----------------
__global__ void k_edge_deg(const int* __restrict__ src, const int* __restrict__ dst,
                           float* degf, int* degi, int E) {
    int e = blockIdx.x * blockDim.x + threadIdx.x;
    if (e < E) {
        atomicAdd(&degf[src[e]], 1.0f);
        atomicAdd(&degi[dst[e]], 1);
    }
}

// norm_out = rsqrt(max(deg_out,1)) (in place over degf), norm_in likewise; graph counts
__global__ void k_node(float* degf_normout, const int* __restrict__ degi, float* norm_in,
                       const int* __restrict__ gid, float* gcnt, int N) {
    int n = blockIdx.x * blockDim.x + threadIdx.x;
    if (n < N) {
        float dout = degf_normout[n];
        degf_normout[n] = rsqrtf(fmaxf(dout, 1.0f));
        norm_in[n] = rsqrtf(fmaxf((float)degi[n], 1.0f));
        atomicAdd(&gcnt[gid[n]], 1.0f);
    }
}

// single-block exclusive scan of deg_in -> row_ptr (N+1 entries)
__global__ void k_scan(const int* __restrict__ deg, int* row_ptr, int n) {
    __shared__ int lds[1024];
    __shared__ int carry;
    if (threadIdx.x == 0) carry = 0;
    __syncthreads();
    for (int base = 0; base < n; base += 1024) {
        int i = base + threadIdx.x;
        int v = (i < n) ? deg[i] : 0;
        lds[threadIdx.x] = v;
        __syncthreads();
        for (int off = 1; off < 1024; off <<= 1) {
            int t = (threadIdx.x >= off) ? lds[threadIdx.x - off] : 0;
            __syncthreads();
            lds[threadIdx.x] += t;
            __syncthreads();
        }
        int incl = lds[threadIdx.x];
        int total = lds[1023];
        if (i < n) row_ptr[i] = carry + (incl - v);
        __syncthreads();
        if (threadIdx.x == 0) carry += total;
        __syncthreads();
    }
    if (threadIdx.x == 0) row_ptr[n] = carry;
}

// fill CSR: for each edge, place src into col_src at a slot of row dst
__global__ void k_fill(const int* __restrict__ src, const int* __restrict__ dst,
                       const int* __restrict__ row_ptr, int* fill_cnt, int* col_src, int E) {
    int e = blockIdx.x * blockDim.x + threadIdx.x;
    if (e < E) {
        int d = dst[e];
        int pos = row_ptr[d] + atomicAdd(&fill_cnt[d], 1);
        col_src[pos] = src[e];
    }
}

// pull-mode aggregation: agg[n][t] = norm_in[n] * sum_{s in nbrs(n)} h[s][t]*norm_out[s]
__global__ void k_agg(const float* __restrict__ hin, const float* __restrict__ norm_out,
                      const float* __restrict__ norm_in, const int* __restrict__ row_ptr,
                      const int* __restrict__ col_src, float* __restrict__ agg) {
    int n = blockIdx.x;
    int t = threadIdx.x;  // 0..127
    int beg = row_ptr[n], end = row_ptr[n + 1];
    float acc = 0.0f;
    int k = beg;
    for (; k + 1 < end; k += 2) {
        int s0 = col_src[k];
        int s1 = col_src[k + 1];
        float w0 = norm_out[s0];
        float w1 = norm_out[s1];
        acc += hin[(size_t)s0 * DD + t] * w0;
        acc += hin[(size_t)s1 * DD + t] * w1;
    }
    if (k < end) {
        int s = col_src[k];
        acc += hin[(size_t)s * DD + t] * norm_out[s];
    }
    agg[(size_t)n * DD + t] = acc * norm_in[n];
}

// GEMM: out[n] = relu(A[n] @ W + b), A:[N,128], W:[128,128]
// block = 256 threads, 64 nodes/block, k staged in 32-wide chunks in LDS
__global__ __launch_bounds__(256) void k_mm(const float* __restrict__ A, const float* __restrict__ Wl,
                                            const float* __restrict__ bl, float* __restrict__ out, int N) {
    __shared__ float Wlds[32 * 128];  // 16 KB
    __shared__ float Alds[64 * 32];   // 8 KB
    int tid = threadIdx.x;
    int tj = tid & 31;   // col quad index: cols tj*4 .. tj*4+3
    int tn = tid >> 5;   // 0..7: nodes tn*8 .. tn*8+7
    int n0 = blockIdx.x * 64;
    float acc[8][4] = {};

    for (int kk = 0; kk < 128; kk += 32) {
        __syncthreads();
        // stage W chunk: rows kk..kk+31, all 128 cols
        for (int q = tid; q < 1024; q += 256) {
            int r = q >> 5;
            int c = (q & 31) * 4;
            *(float4*)&Wlds[r * 128 + c] = *(const float4*)&Wl[(size_t)(kk + r) * 128 + c];
        }
        // stage A chunk: 64 rows x 32 cols
        for (int q = tid; q < 512; q += 256) {
            int r = q >> 3;
            int c = (q & 7) * 4;
            int n = n0 + r;
            float4 v = make_float4(0.f, 0.f, 0.f, 0.f);
            if (n < N) v = *(const float4*)&A[(size_t)n * 128 + kk + c];
            *(float4*)&Alds[r * 32 + c] = v;
        }
        __syncthreads();
        #pragma unroll 4
        for (int kl = 0; kl < 32; ++kl) {
            float4 w = *(float4*)&Wlds[kl * 128 + tj * 4];
            #pragma unroll
            for (int i = 0; i < 8; ++i) {
                float a = Alds[(tn * 8 + i) * 32 + kl];
                acc[i][0] += a * w.x;
                acc[i][1] += a * w.y;
                acc[i][2] += a * w.z;
                acc[i][3] += a * w.w;
            }
        }
    }
    float4 bv = *(const float4*)&bl[tj * 4];
    #pragma unroll
    for (int i = 0; i < 8; ++i) {
        int n = n0 + tn * 8 + i;
        if (n < N) {
            float4 o;
            o.x = fmaxf(acc[i][0] + bv.x, 0.f);
            o.y = fmaxf(acc[i][1] + bv.y, 0.f);
            o.z = fmaxf(acc[i][2] + bv.z, 0.f);
            o.w = fmaxf(acc[i][3] + bv.w, 0.f);
            *(float4*)&out[(size_t)n * 128 + tj * 4] = o;
        }
    }
}

// pooled mean readout; graph_ids sorted -> register accumulate, flush on boundary
__global__ void k_pool(const float* __restrict__ h, const int* __restrict__ gid,
                       const float* __restrict__ gcnt, float* out, int N) {
    int t = threadIdx.x;  // 0..127
    int n0 = blockIdx.x * 128;
    if (n0 >= N) return;
    int nend = min(n0 + 128, N);
    float acc = 0.0f;
    int cur = gid[n0];
    for (int n = n0; n < nend; ++n) {
        int g = gid[n];
        if (g != cur) {
            atomicAdd(&out[cur * DD + t], acc / fmaxf(gcnt[cur], 1.0f));
            acc = 0.0f;
            cur = g;
        }
        acc += h[(size_t)n * DD + t];
    }
    atomicAdd(&out[cur * DD + t], acc / fmaxf(gcnt[cur], 1.0f));
}

extern "C" void kernel_launch(void* const* d_in, const int* in_sizes, int n_in,
                              void* d_out, int out_size, void* d_ws, size_t ws_size,
                              hipStream_t stream) {
    const float* feats = (const float*)d_in[0];
    const float* W = (const float*)d_in[1];
    const float* b = (const float*)d_in[2];
    const int* src = (const int*)d_in[3];
    const int* dst = (const int*)d_in[4];
    const int* gid = (const int*)d_in[5];
    float* out = (float*)d_out;
    const int N = in_sizes[0] / DD;  // 50000
    const int E = in_sizes[3];       // 800000

    char* ws = (char*)d_ws;
    size_t off = 0;
    auto take = [&](size_t bytes) {
        char* p = ws + off;
        off = (off + bytes + 255) & ~(size_t)255;
        return p;
    };
    float* norm_out = (float*)take((size_t)N * 4);        // deg_out accum, then norm_out
    float* norm_in  = (float*)take((size_t)N * 4);
    int*   deg_in   = (int*)take((size_t)N * 4);
    int*   row_ptr  = (int*)take((size_t)(N + 1) * 4);
    int*   fill_cnt = (int*)take((size_t)N * 4);
    int*   col_src  = (int*)take((size_t)E * 4);
    float* gcnt     = (float*)take((size_t)GG * 4);
    float* hbuf     = (float*)take((size_t)N * DD * 4);
    float* aggbuf   = (float*)take((size_t)N * DD * 4);

    hipMemsetAsync(norm_out, 0, (size_t)N * 4, stream);
    hipMemsetAsync(deg_in, 0, (size_t)N * 4, stream);
    hipMemsetAsync(fill_cnt, 0, (size_t)N * 4, stream);
    hipMemsetAsync(gcnt, 0, (size_t)GG * 4, stream);
    hipMemsetAsync(d_out, 0, (size_t)out_size * 4, stream);

    k_edge_deg<<<(E + 255) / 256, 256, 0, stream>>>(src, dst, norm_out, deg_in, E);
    k_node<<<(N + 255) / 256, 256, 0, stream>>>(norm_out, deg_in, norm_in, gid, gcnt, N);
    k_scan<<<1, 1024, 0, stream>>>(deg_in, row_ptr, N);
    k_fill<<<(E + 255) / 256, 256, 0, stream>>>(src, dst, row_ptr, fill_cnt, col_src, E);

    const float* hin = feats;
    for (int l = 0; l < 3; ++l) {
        k_agg<<<N, 128, 0, stream>>>(hin, norm_out, norm_in, row_ptr, col_src, aggbuf);
        k_mm<<<(N + 63) / 64, 256, 0, stream>>>(aggbuf, W + (size_t)l * DD * DD, b + (size_t)l * DD, hbuf, N);
        hin = hbuf;
    }
    k_pool<<<(N + 127) / 128, 128, 0, stream>>>(hbuf, gid, gcnt, out, N);
}

// Round 2
// 589.236 us; speedup vs baseline: 1.1745x; 1.1745x over previous
//
#include <hip/hip_runtime.h>

#define DD 128
#define GG 256
#define NPB 2  // nodes per block in k_agg

// ---------------- degree accumulation ----------------
__global__ void k_edge_deg(const int* __restrict__ src, const int* __restrict__ dst,
                           float* degf, int* degi, int E) {
    int e = blockIdx.x * blockDim.x + threadIdx.x;
    if (e < E) {
        atomicAdd(&degf[src[e]], 1.0f);
        atomicAdd(&degi[dst[e]], 1);
    }
}

// norm_out = rsqrt(max(deg_out,1)) (in place over degf), norm_in likewise; graph counts
__global__ void k_node(float* degf_normout, const int* __restrict__ degi, float* norm_in,
                       const int* __restrict__ gid, float* gcnt, int N) {
    int n = blockIdx.x * blockDim.x + threadIdx.x;
    if (n < N) {
        float dout = degf_normout[n];
        degf_normout[n] = rsqrtf(fmaxf(dout, 1.0f));
        norm_in[n] = rsqrtf(fmaxf((float)degi[n], 1.0f));
        atomicAdd(&gcnt[gid[n]], 1.0f);
    }
}

// ---------------- 3-phase scan: deg_in -> row_ptr ----------------
// phase A: each block (256 thr) sums a 1024-elem chunk -> bsum[blk]
__global__ __launch_bounds__(256) void k_scan_a(const int* __restrict__ deg, int* bsum, int n) {
    __shared__ int wsum[4];
    int base = blockIdx.x * 1024 + threadIdx.x * 4;
    int s = 0;
    #pragma unroll
    for (int j = 0; j < 4; ++j) s += (base + j < n) ? deg[base + j] : 0;
    #pragma unroll
    for (int off = 32; off; off >>= 1) s += __shfl_xor(s, off);
    int lane = threadIdx.x & 63, w = threadIdx.x >> 6;
    if (lane == 0) wsum[w] = s;
    __syncthreads();
    if (threadIdx.x == 0) bsum[blockIdx.x] = wsum[0] + wsum[1] + wsum[2] + wsum[3];
}

// phase B: single wave scans bsum (exclusive, in place), writes total to row_ptr[n]
__global__ void k_scan_b(int* bsum, int nblk, int* row_ptr, int n) {
    int lane = threadIdx.x;  // 64 threads
    int carry = 0;
    for (int base = 0; base < nblk; base += 64) {
        int i = base + lane;
        int v = (i < nblk) ? bsum[i] : 0;
        int s = v;
        #pragma unroll
        for (int off = 1; off < 64; off <<= 1) {
            int u = __shfl_up(s, off);
            if (lane >= off) s += u;
        }
        if (i < nblk) bsum[i] = carry + s - v;  // exclusive
        carry += __shfl(s, 63);
    }
    if (lane == 0) row_ptr[n] = carry;
}

// phase C: each block scans its 1024-elem chunk with bsum offset -> row_ptr (exclusive)
__global__ __launch_bounds__(256) void k_scan_c(const int* __restrict__ deg, const int* __restrict__ bsum,
                                                int* row_ptr, int n) {
    __shared__ int wsum[4];
    int t = threadIdx.x;
    int base = blockIdx.x * 1024 + t * 4;
    int v[4];
    #pragma unroll
    for (int j = 0; j < 4; ++j) v[j] = (base + j < n) ? deg[base + j] : 0;
    int ts = v[0] + v[1] + v[2] + v[3];
    int lane = t & 63, w = t >> 6;
    int incl = ts;
    #pragma unroll
    for (int off = 1; off < 64; off <<= 1) {
        int u = __shfl_up(incl, off);
        if (lane >= off) incl += u;
    }
    if (lane == 63) wsum[w] = incl;
    __syncthreads();
    int woff = 0;
    for (int j = 0; j < w; ++j) woff += wsum[j];
    int run = bsum[blockIdx.x] + woff + incl - ts;
    #pragma unroll
    for (int j = 0; j < 4; ++j) {
        if (base + j < n) row_ptr[base + j] = run;
        run += v[j];
    }
}

// fill CSR: for each edge, place src into col_src at a slot of row dst
__global__ void k_fill(const int* __restrict__ src, const int* __restrict__ dst,
                       const int* __restrict__ row_ptr, int* fill_cnt, int* col_src, int E) {
    int e = blockIdx.x * blockDim.x + threadIdx.x;
    if (e < E) {
        int d = dst[e];
        int pos = row_ptr[d] + atomicAdd(&fill_cnt[d], 1);
        col_src[pos] = src[e];
    }
}

// pull-mode aggregation, vectorized:
// per node: 32 col-quad threads (float4) x 4 neighbor lanes; LDS reduce over lanes.
__global__ __launch_bounds__(256) void k_agg(const float* __restrict__ hin, const float* __restrict__ norm_out,
                                             const float* __restrict__ norm_in, const int* __restrict__ row_ptr,
                                             const int* __restrict__ col_src, float* __restrict__ agg, int N) {
    __shared__ float4 red[NPB][4][32];
    int tid = threadIdx.x;
    int local = tid & 127;
    int which = tid >> 7;
    int tc = local & 31;  // col quad: cols tc*4..tc*4+3
    int jn = local >> 5;  // neighbor lane 0..3
    int n = blockIdx.x * NPB + which;
    float4 acc = make_float4(0.f, 0.f, 0.f, 0.f);
    if (n < N) {
        int beg = row_ptr[n], end = row_ptr[n + 1];
        int k = beg + jn;
        for (; k + 4 < end; k += 8) {
            int s0 = col_src[k];
            int s1 = col_src[k + 4];
            float w0 = norm_out[s0];
            float w1 = norm_out[s1];
            float4 v0 = *(const float4*)&hin[(size_t)s0 * DD + tc * 4];
            float4 v1 = *(const float4*)&hin[(size_t)s1 * DD + tc * 4];
            acc.x += v0.x * w0 + v1.x * w1;
            acc.y += v0.y * w0 + v1.y * w1;
            acc.z += v0.z * w0 + v1.z * w1;
            acc.w += v0.w * w0 + v1.w * w1;
        }
        if (k < end) {
            int s = col_src[k];
            float w = norm_out[s];
            float4 v = *(const float4*)&hin[(size_t)s * DD + tc * 4];
            acc.x += v.x * w;
            acc.y += v.y * w;
            acc.z += v.z * w;
            acc.w += v.w * w;
        }
    }
    red[which][jn][tc] = acc;
    __syncthreads();
    if (jn == 0 && n < N) {
        float4 a0 = red[which][0][tc];
        float4 a1 = red[which][1][tc];
        float4 a2 = red[which][2][tc];
        float4 a3 = red[which][3][tc];
        float ni = norm_in[n];
        float4 o;
        o.x = (a0.x + a1.x + a2.x + a3.x) * ni;
        o.y = (a0.y + a1.y + a2.y + a3.y) * ni;
        o.z = (a0.z + a1.z + a2.z + a3.z) * ni;
        o.w = (a0.w + a1.w + a2.w + a3.w) * ni;
        *(float4*)&agg[(size_t)n * DD + tc * 4] = o;
    }
}

// GEMM: out[n] = relu(A[n] @ W + b), A:[N,128], W:[128,128]
__global__ __launch_bounds__(256) void k_mm(const float* __restrict__ A, const float* __restrict__ Wl,
                                            const float* __restrict__ bl, float* __restrict__ out, int N) {
    __shared__ float Wlds[32 * 128];  // 16 KB
    __shared__ float Alds[64 * 32];   // 8 KB
    int tid = threadIdx.x;
    int tj = tid & 31;
    int tn = tid >> 5;
    int n0 = blockIdx.x * 64;
    float acc[8][4] = {};

    for (int kk = 0; kk < 128; kk += 32) {
        __syncthreads();
        for (int q = tid; q < 1024; q += 256) {
            int r = q >> 5;
            int c = (q & 31) * 4;
            *(float4*)&Wlds[r * 128 + c] = *(const float4*)&Wl[(size_t)(kk + r) * 128 + c];
        }
        for (int q = tid; q < 512; q += 256) {
            int r = q >> 3;
            int c = (q & 7) * 4;
            int n = n0 + r;
            float4 v = make_float4(0.f, 0.f, 0.f, 0.f);
            if (n < N) v = *(const float4*)&A[(size_t)n * 128 + kk + c];
            *(float4*)&Alds[r * 32 + c] = v;
        }
        __syncthreads();
        #pragma unroll 4
        for (int kl = 0; kl < 32; ++kl) {
            float4 w = *(float4*)&Wlds[kl * 128 + tj * 4];
            #pragma unroll
            for (int i = 0; i < 8; ++i) {
                float a = Alds[(tn * 8 + i) * 32 + kl];
                acc[i][0] += a * w.x;
                acc[i][1] += a * w.y;
                acc[i][2] += a * w.z;
                acc[i][3] += a * w.w;
            }
        }
    }
    float4 bv = *(const float4*)&bl[tj * 4];
    #pragma unroll
    for (int i = 0; i < 8; ++i) {
        int n = n0 + tn * 8 + i;
        if (n < N) {
            float4 o;
            o.x = fmaxf(acc[i][0] + bv.x, 0.f);
            o.y = fmaxf(acc[i][1] + bv.y, 0.f);
            o.z = fmaxf(acc[i][2] + bv.z, 0.f);
            o.w = fmaxf(acc[i][3] + bv.w, 0.f);
            *(float4*)&out[(size_t)n * 128 + tj * 4] = o;
        }
    }
}

// pooled mean readout; graph_ids sorted -> register accumulate, flush on boundary
__global__ void k_pool(const float* __restrict__ h, const int* __restrict__ gid,
                       const float* __restrict__ gcnt, float* out, int N) {
    int t = threadIdx.x;  // 0..127
    int n0 = blockIdx.x * 128;
    if (n0 >= N) return;
    int nend = min(n0 + 128, N);
    float acc = 0.0f;
    int cur = gid[n0];
    for (int n = n0; n < nend; ++n) {
        int g = gid[n];
        if (g != cur) {
            atomicAdd(&out[cur * DD + t], acc / fmaxf(gcnt[cur], 1.0f));
            acc = 0.0f;
            cur = g;
        }
        acc += h[(size_t)n * DD + t];
    }
    atomicAdd(&out[cur * DD + t], acc / fmaxf(gcnt[cur], 1.0f));
}

extern "C" void kernel_launch(void* const* d_in, const int* in_sizes, int n_in,
                              void* d_out, int out_size, void* d_ws, size_t ws_size,
                              hipStream_t stream) {
    const float* feats = (const float*)d_in[0];
    const float* W = (const float*)d_in[1];
    const float* b = (const float*)d_in[2];
    const int* src = (const int*)d_in[3];
    const int* dst = (const int*)d_in[4];
    const int* gid = (const int*)d_in[5];
    float* out = (float*)d_out;
    const int N = in_sizes[0] / DD;  // 50000
    const int E = in_sizes[3];       // 800000

    char* ws = (char*)d_ws;
    size_t off = 0;
    auto take = [&](size_t bytes) {
        char* p = ws + off;
        off = (off + bytes + 255) & ~(size_t)255;
        return p;
    };
    float* norm_out = (float*)take((size_t)N * 4);
    float* norm_in  = (float*)take((size_t)N * 4);
    int*   deg_in   = (int*)take((size_t)N * 4);
    int*   row_ptr  = (int*)take((size_t)(N + 1) * 4);
    int*   fill_cnt = (int*)take((size_t)N * 4);
    int*   col_src  = (int*)take((size_t)E * 4);
    float* gcnt     = (float*)take((size_t)GG * 4);
    int*   bsum     = (int*)take((size_t)1024 * 4);
    float* hbuf     = (float*)take((size_t)N * DD * 4);
    float* aggbuf   = (float*)take((size_t)N * DD * 4);

    hipMemsetAsync(norm_out, 0, (size_t)N * 4, stream);
    hipMemsetAsync(deg_in, 0, (size_t)N * 4, stream);
    hipMemsetAsync(fill_cnt, 0, (size_t)N * 4, stream);
    hipMemsetAsync(gcnt, 0, (size_t)GG * 4, stream);
    hipMemsetAsync(d_out, 0, (size_t)out_size * 4, stream);

    const int nblk = (N + 1023) / 1024;  // 49

    k_edge_deg<<<(E + 255) / 256, 256, 0, stream>>>(src, dst, norm_out, deg_in, E);
    k_node<<<(N + 255) / 256, 256, 0, stream>>>(norm_out, deg_in, norm_in, gid, gcnt, N);
    k_scan_a<<<nblk, 256, 0, stream>>>(deg_in, bsum, N);
    k_scan_b<<<1, 64, 0, stream>>>(bsum, nblk, row_ptr, N);
    k_scan_c<<<nblk, 256, 0, stream>>>(deg_in, bsum, row_ptr, N);
    k_fill<<<(E + 255) / 256, 256, 0, stream>>>(src, dst, row_ptr, fill_cnt, col_src, E);

    const float* hin = feats;
    for (int l = 0; l < 3; ++l) {
        k_agg<<<(N + NPB - 1) / NPB, 256, 0, stream>>>(hin, norm_out, norm_in, row_ptr, col_src, aggbuf, N);
        k_mm<<<(N + 63) / 64, 256, 0, stream>>>(aggbuf, W + (size_t)l * DD * DD, b + (size_t)l * DD, hbuf, N);
        hin = hbuf;
    }
    k_pool<<<(N + 127) / 128, 128, 0, stream>>>(hbuf, gid, gcnt, out, N);
}

// Round 3
// 494.192 us; speedup vs baseline: 1.4003x; 1.1923x over previous
//
#include <hip/hip_runtime.h>

#define DD 128
#define GG 256

// ---------------- degree accumulation ----------------
__global__ void k_edge_deg(const int* __restrict__ src, const int* __restrict__ dst,
                           float* degf, int* degi, int E) {
    int e = blockIdx.x * blockDim.x + threadIdx.x;
    if (e < E) {
        atomicAdd(&degf[src[e]], 1.0f);
        atomicAdd(&degi[dst[e]], 1);
    }
}

// norm_out = rsqrt(max(deg_out,1)) in place; norm_in likewise. No atomics.
__global__ void k_node(float* degf_normout, const int* __restrict__ degi, float* norm_in, int N) {
    int n = blockIdx.x * blockDim.x + threadIdx.x;
    if (n < N) {
        degf_normout[n] = rsqrtf(fmaxf(degf_normout[n], 1.0f));
        norm_in[n] = rsqrtf(fmaxf((float)degi[n], 1.0f));
    }
}

// g_start[g] = lower_bound(gid, g), g in [0, G]; gid sorted.
__global__ void k_gstart(const int* __restrict__ gid, int* g_start, int N, int G) {
    int g = blockIdx.x * blockDim.x + threadIdx.x;
    if (g > G) return;
    int lo = 0, hi = N;
    while (lo < hi) {
        int mid = (lo + hi) >> 1;
        if (gid[mid] < g) lo = mid + 1; else hi = mid;
    }
    g_start[g] = lo;
}

// ---------------- 3-phase scan: deg_in -> row_ptr ----------------
__global__ __launch_bounds__(256) void k_scan_a(const int* __restrict__ deg, int* bsum, int n) {
    __shared__ int wsum[4];
    int base = blockIdx.x * 1024 + threadIdx.x * 4;
    int s = 0;
    #pragma unroll
    for (int j = 0; j < 4; ++j) s += (base + j < n) ? deg[base + j] : 0;
    #pragma unroll
    for (int off = 32; off; off >>= 1) s += __shfl_xor(s, off);
    int lane = threadIdx.x & 63, w = threadIdx.x >> 6;
    if (lane == 0) wsum[w] = s;
    __syncthreads();
    if (threadIdx.x == 0) bsum[blockIdx.x] = wsum[0] + wsum[1] + wsum[2] + wsum[3];
}

__global__ void k_scan_b(int* bsum, int nblk, int* row_ptr, int n) {
    int lane = threadIdx.x;  // 64 threads
    int carry = 0;
    for (int base = 0; base < nblk; base += 64) {
        int i = base + lane;
        int v = (i < nblk) ? bsum[i] : 0;
        int s = v;
        #pragma unroll
        for (int off = 1; off < 64; off <<= 1) {
            int u = __shfl_up(s, off);
            if (lane >= off) s += u;
        }
        if (i < nblk) bsum[i] = carry + s - v;  // exclusive
        carry += __shfl(s, 63);
    }
    if (lane == 0) row_ptr[n] = carry;
}

__global__ __launch_bounds__(256) void k_scan_c(const int* __restrict__ deg, const int* __restrict__ bsum,
                                                int* row_ptr, int n) {
    __shared__ int wsum[4];
    int t = threadIdx.x;
    int base = blockIdx.x * 1024 + t * 4;
    int v[4];
    #pragma unroll
    for (int j = 0; j < 4; ++j) v[j] = (base + j < n) ? deg[base + j] : 0;
    int ts = v[0] + v[1] + v[2] + v[3];
    int lane = t & 63, w = t >> 6;
    int incl = ts;
    #pragma unroll
    for (int off = 1; off < 64; off <<= 1) {
        int u = __shfl_up(incl, off);
        if (lane >= off) incl += u;
    }
    if (lane == 63) wsum[w] = incl;
    __syncthreads();
    int woff = 0;
    for (int j = 0; j < w; ++j) woff += wsum[j];
    int run = bsum[blockIdx.x] + woff + incl - ts;
    #pragma unroll
    for (int j = 0; j < 4; ++j) {
        if (base + j < n) row_ptr[base + j] = run;
        run += v[j];
    }
}

// fill CSR: for each edge, place src into col_src at a slot of row dst
__global__ void k_fill(const int* __restrict__ src, const int* __restrict__ dst,
                       const int* __restrict__ row_ptr, int* fill_cnt, int* col_src, int E) {
    int e = blockIdx.x * blockDim.x + threadIdx.x;
    if (e < E) {
        int d = dst[e];
        int pos = row_ptr[d] + atomicAdd(&fill_cnt[d], 1);
        col_src[pos] = src[e];
    }
}

// pre-scale rows: hn[n] = h[n] * norm_out[n]  (float4 per thread)
__global__ void k_scale(const float* __restrict__ h, const float* __restrict__ norm_out,
                        float* __restrict__ hn, int N) {
    int i = blockIdx.x * blockDim.x + threadIdx.x;  // over N*32 float4s
    if (i < N * 32) {
        int n = i >> 5;
        float4 v = ((const float4*)h)[i];
        float s = norm_out[n];
        v.x *= s; v.y *= s; v.z *= s; v.w *= s;
        ((float4*)hn)[i] = v;
    }
}

// pull-mode aggregation: input rows are pre-scaled by norm_out.
// 32 threads/node (float4 each), 8 nodes per 256-thread block, unroll x4.
__global__ __launch_bounds__(256) void k_agg(const float* __restrict__ hn, const float* __restrict__ norm_in,
                                             const int* __restrict__ row_ptr, const int* __restrict__ col_src,
                                             float* __restrict__ agg, int N) {
    int t = threadIdx.x;
    int tc = t & 31;          // col quad
    int n = blockIdx.x * 8 + (t >> 5);
    if (n >= N) return;
    int beg = row_ptr[n], end = row_ptr[n + 1];
    float4 acc = make_float4(0.f, 0.f, 0.f, 0.f);
    int k = beg;
    for (; k + 3 < end; k += 4) {
        int s0 = col_src[k];
        int s1 = col_src[k + 1];
        int s2 = col_src[k + 2];
        int s3 = col_src[k + 3];
        float4 v0 = *(const float4*)&hn[(size_t)s0 * DD + tc * 4];
        float4 v1 = *(const float4*)&hn[(size_t)s1 * DD + tc * 4];
        float4 v2 = *(const float4*)&hn[(size_t)s2 * DD + tc * 4];
        float4 v3 = *(const float4*)&hn[(size_t)s3 * DD + tc * 4];
        acc.x += v0.x + v1.x + v2.x + v3.x;
        acc.y += v0.y + v1.y + v2.y + v3.y;
        acc.z += v0.z + v1.z + v2.z + v3.z;
        acc.w += v0.w + v1.w + v2.w + v3.w;
    }
    for (; k < end; ++k) {
        int s = col_src[k];
        float4 v = *(const float4*)&hn[(size_t)s * DD + tc * 4];
        acc.x += v.x; acc.y += v.y; acc.z += v.z; acc.w += v.w;
    }
    float ni = norm_in[n];
    acc.x *= ni; acc.y *= ni; acc.z *= ni; acc.w *= ni;
    *(float4*)&agg[(size_t)n * DD + tc * 4] = acc;
}

// GEMM: out[n] = relu(A[n] @ W + b) [* scale[n] if scale], A:[N,128], W:[128,128]
__global__ __launch_bounds__(256) void k_mm(const float* __restrict__ A, const float* __restrict__ Wl,
                                            const float* __restrict__ bl, const float* __restrict__ scale,
                                            float* __restrict__ out, int N) {
    __shared__ float Wlds[32 * 128];  // 16 KB
    __shared__ float Alds[64 * 32];   // 8 KB
    int tid = threadIdx.x;
    int tj = tid & 31;
    int tn = tid >> 5;
    int n0 = blockIdx.x * 64;
    float acc[8][4] = {};

    for (int kk = 0; kk < 128; kk += 32) {
        __syncthreads();
        for (int q = tid; q < 1024; q += 256) {
            int r = q >> 5;
            int c = (q & 31) * 4;
            *(float4*)&Wlds[r * 128 + c] = *(const float4*)&Wl[(size_t)(kk + r) * 128 + c];
        }
        for (int q = tid; q < 512; q += 256) {
            int r = q >> 3;
            int c = (q & 7) * 4;
            int n = n0 + r;
            float4 v = make_float4(0.f, 0.f, 0.f, 0.f);
            if (n < N) v = *(const float4*)&A[(size_t)n * 128 + kk + c];
            *(float4*)&Alds[r * 32 + c] = v;
        }
        __syncthreads();
        #pragma unroll 4
        for (int kl = 0; kl < 32; ++kl) {
            float4 w = *(float4*)&Wlds[kl * 128 + tj * 4];
            #pragma unroll
            for (int i = 0; i < 8; ++i) {
                float a = Alds[(tn * 8 + i) * 32 + kl];
                acc[i][0] += a * w.x;
                acc[i][1] += a * w.y;
                acc[i][2] += a * w.z;
                acc[i][3] += a * w.w;
            }
        }
    }
    float4 bv = *(const float4*)&bl[tj * 4];
    #pragma unroll
    for (int i = 0; i < 8; ++i) {
        int n = n0 + tn * 8 + i;
        if (n < N) {
            float sc = scale ? scale[n] : 1.0f;
            float4 o;
            o.x = fmaxf(acc[i][0] + bv.x, 0.f) * sc;
            o.y = fmaxf(acc[i][1] + bv.y, 0.f) * sc;
            o.z = fmaxf(acc[i][2] + bv.z, 0.f) * sc;
            o.w = fmaxf(acc[i][3] + bv.w, 0.f) * sc;
            *(float4*)&out[(size_t)n * 128 + tj * 4] = o;
        }
    }
}

// pooled mean readout: one block per graph, contiguous row range, no atomics.
__global__ __launch_bounds__(128) void k_pool(const float* __restrict__ h, const int* __restrict__ g_start,
                                              float* __restrict__ out) {
    int g = blockIdx.x;
    int t = threadIdx.x;  // 0..127
    int beg = g_start[g], end = g_start[g + 1];
    float acc = 0.0f;
    int n = beg;
    for (; n + 3 < end; n += 4) {
        float a0 = h[(size_t)n * DD + t];
        float a1 = h[(size_t)(n + 1) * DD + t];
        float a2 = h[(size_t)(n + 2) * DD + t];
        float a3 = h[(size_t)(n + 3) * DD + t];
        acc += a0 + a1 + a2 + a3;
    }
    for (; n < end; ++n) acc += h[(size_t)n * DD + t];
    float cnt = (float)(end - beg);
    out[(size_t)g * DD + t] = acc / fmaxf(cnt, 1.0f);
}

extern "C" void kernel_launch(void* const* d_in, const int* in_sizes, int n_in,
                              void* d_out, int out_size, void* d_ws, size_t ws_size,
                              hipStream_t stream) {
    const float* feats = (const float*)d_in[0];
    const float* W = (const float*)d_in[1];
    const float* b = (const float*)d_in[2];
    const int* src = (const int*)d_in[3];
    const int* dst = (const int*)d_in[4];
    const int* gid = (const int*)d_in[5];
    float* out = (float*)d_out;
    const int N = in_sizes[0] / DD;  // 50000
    const int E = in_sizes[3];       // 800000

    char* ws = (char*)d_ws;
    size_t off = 0;
    auto take = [&](size_t bytes) {
        char* p = ws + off;
        off = (off + bytes + 255) & ~(size_t)255;
        return p;
    };
    float* norm_out = (float*)take((size_t)N * 4);
    float* norm_in  = (float*)take((size_t)N * 4);
    int*   deg_in   = (int*)take((size_t)N * 4);
    int*   row_ptr  = (int*)take((size_t)(N + 1) * 4);
    int*   fill_cnt = (int*)take((size_t)N * 4);
    int*   col_src  = (int*)take((size_t)E * 4);
    int*   g_start  = (int*)take((size_t)(GG + 1) * 4);
    int*   bsum     = (int*)take((size_t)1024 * 4);
    float* X        = (float*)take((size_t)N * DD * 4);  // scaled h
    float* Y        = (float*)take((size_t)N * DD * 4);  // agg output

    hipMemsetAsync(norm_out, 0, (size_t)N * 4, stream);
    hipMemsetAsync(deg_in, 0, (size_t)N * 4, stream);
    hipMemsetAsync(fill_cnt, 0, (size_t)N * 4, stream);

    const int nblk = (N + 1023) / 1024;  // 49

    k_edge_deg<<<(E + 255) / 256, 256, 0, stream>>>(src, dst, norm_out, deg_in, E);
    k_node<<<(N + 255) / 256, 256, 0, stream>>>(norm_out, deg_in, norm_in, N);
    k_gstart<<<1, 512, 0, stream>>>(gid, g_start, N, GG);
    k_scan_a<<<nblk, 256, 0, stream>>>(deg_in, bsum, N);
    k_scan_b<<<1, 64, 0, stream>>>(bsum, nblk, row_ptr, N);
    k_scan_c<<<nblk, 256, 0, stream>>>(deg_in, bsum, row_ptr, N);
    k_fill<<<(E + 255) / 256, 256, 0, stream>>>(src, dst, row_ptr, fill_cnt, col_src, E);

    // layer 0 input: feats pre-scaled by norm_out
    k_scale<<<(N * 32 + 255) / 256, 256, 0, stream>>>(feats, norm_out, X, N);

    for (int l = 0; l < 3; ++l) {
        k_agg<<<(N + 7) / 8, 256, 0, stream>>>(X, norm_in, row_ptr, col_src, Y, N);
        const float* sc = (l < 2) ? norm_out : nullptr;
        k_mm<<<(N + 63) / 64, 256, 0, stream>>>(Y, W + (size_t)l * DD * DD, b + (size_t)l * DD, sc, X, N);
    }
    k_pool<<<GG, 128, 0, stream>>>(X, g_start, out);
}